// Round 6
// baseline (201.777 us; speedup 1.0000x reference)
//
#include <hip/hip_runtime.h>
#include <cstdint>

#define HW  128
#define NCH 256
#define NOC 18      // G*K*K
#define PLANE (HW * HW)
#define EPSBN 1e-5f

typedef __attribute__((ext_vector_type(8)))  short bf16x8;
typedef __attribute__((ext_vector_type(16))) float f32x16;

__device__ __forceinline__ unsigned short f2bf(float f) {
    union { float f; uint32_t u; } c; c.f = f;
    uint32_t u = c.u;
    uint32_t r = u + 0x7FFFu + ((u >> 16) & 1u);   // RNE
    return (unsigned short)(r >> 16);
}

// swizzled LDS byte offset for tile [slot(4)][px(130)][ic(32)] bf16
// px stride = 64 B; XOR px bits into the 16B-granule index so a wave's
// 32 consecutive-px b128 reads spread uniformly over the banks.
__device__ __forceinline__ int lds_off(int slot, int px, int ic) {
    int b = ((slot * 130 + px) * 32 + ic) * 2;
    return b ^ ((px & 6) << 3);
}

// ------------- Kernel W: pack weights -> wB[tap][ic>>3][oc(32 pad)][ic&7] bf16
__global__ __launch_bounds__(256) void pasa_wprep(
    const float* __restrict__ w, unsigned short* __restrict__ wB)
{
    int idx = blockIdx.x * 256 + threadIdx.x;      // 9*32*32*8 = 73728
    int icl = idx & 7;
    int oc  = (idx >> 3) & 31;
    int icb = (idx >> 8) & 31;
    int tap = idx >> 13;
    int ic  = icb * 8 + icl;
    float v = (oc < NOC) ? w[((size_t)oc * NCH + ic) * 9 + tap] : 0.0f;
    wB[idx] = f2bf(v);
}

// ------------- Kernel A: implicit-GEMM conv + BN + softmax (fused) ---------
// 8 chunks of 32 ic; LDS 33.3 KB -> 4 blocks/CU = 8 waves/SIMD so staging
// stalls of one block hide under other blocks' MFMA phase.
__global__ __launch_bounds__(512, 8) void pasa_conv_mfma(
    const float* __restrict__ x, const unsigned short* __restrict__ wB,
    const float* __restrict__ gamma, const float* __restrict__ beta,
    const float* __restrict__ rmean, const float* __restrict__ rvar,
    float* __restrict__ sigma)
{
    __shared__ __align__(16) char lds[4 * 130 * 32 * 2];   // 33280 B

    int flat = blockIdx.x;                 // [0,512)
    int nf   = (flat & 7) * 64 + (flat >> 3);  // XCD gets one image
    const int n  = nf >> 6;
    const int y0 = (nf & 63) * 2;

    const int tid  = threadIdx.x;
    const int lane = tid & 63;
    const int wv   = tid >> 6;             // wave 0..7
    const int m    = lane & 31;            // MFMA col (pixel in tile)
    const int hi   = lane >> 5;            // k-half selector

    const int team = tid >> 7;             // 0..3 -> LDS slot
    const int p128 = tid & 127;            // global px
    int grow;
    if      (team == 0) grow = (y0 == 0) ? 1 : y0 - 1;
    else if (team == 1) grow = y0;
    else if (team == 2) grow = y0 + 1;
    else                grow = (y0 + 1 == HW - 1) ? HW - 2 : y0 + 2;

    const float* xrow = x + (size_t)n * NCH * PLANE + (size_t)grow * HW;

    const int out_row = wv >> 2;
    const int px_tile = (wv & 3) * 32;

    f32x16 acc;
    #pragma unroll
    for (int i = 0; i < 16; ++i) acc[i] = 0.0f;

    for (int chunk = 0; chunk < 8; ++chunk) {
        const int icg0 = chunk * 32;
        // ---- stage 32 ic x 4 rows x 130 px (bf16, swizzled) ----
        #pragma unroll
        for (int it = 0; it < 4; ++it) {
            const int ic = icg0 + it * 8;
            float v[8];
            #pragma unroll
            for (int i = 0; i < 8; ++i)
                v[i] = xrow[(size_t)(ic + i) * PLANE + p128];
            int4 d;
            d.x = (uint32_t)f2bf(v[0]) | ((uint32_t)f2bf(v[1]) << 16);
            d.y = (uint32_t)f2bf(v[2]) | ((uint32_t)f2bf(v[3]) << 16);
            d.z = (uint32_t)f2bf(v[4]) | ((uint32_t)f2bf(v[5]) << 16);
            d.w = (uint32_t)f2bf(v[6]) | ((uint32_t)f2bf(v[7]) << 16);
            *(int4*)(lds + lds_off(team, p128 + 1, it * 8)) = d;
            if (p128 == 0) {               // left halo: reflect px=1
                float h[8];
                #pragma unroll
                for (int i = 0; i < 8; ++i)
                    h[i] = xrow[(size_t)(ic + i) * PLANE + 1];
                int4 e;
                e.x = (uint32_t)f2bf(h[0]) | ((uint32_t)f2bf(h[1]) << 16);
                e.y = (uint32_t)f2bf(h[2]) | ((uint32_t)f2bf(h[3]) << 16);
                e.z = (uint32_t)f2bf(h[4]) | ((uint32_t)f2bf(h[5]) << 16);
                e.w = (uint32_t)f2bf(h[6]) | ((uint32_t)f2bf(h[7]) << 16);
                *(int4*)(lds + lds_off(team, 0, it * 8)) = e;
            }
            if (p128 == 127) {             // right halo: reflect px=126
                float h[8];
                #pragma unroll
                for (int i = 0; i < 8; ++i)
                    h[i] = xrow[(size_t)(ic + i) * PLANE + 126];
                int4 e;
                e.x = (uint32_t)f2bf(h[0]) | ((uint32_t)f2bf(h[1]) << 16);
                e.y = (uint32_t)f2bf(h[2]) | ((uint32_t)f2bf(h[3]) << 16);
                e.z = (uint32_t)f2bf(h[4]) | ((uint32_t)f2bf(h[5]) << 16);
                e.w = (uint32_t)f2bf(h[6]) | ((uint32_t)f2bf(h[7]) << 16);
                *(int4*)(lds + lds_off(team, 129, it * 8)) = e;
            }
        }
        __syncthreads();
        // ---- MFMA: 9 taps x 2 k-steps, D = W·X ----
        #pragma unroll
        for (int tap = 0; tap < 9; ++tap) {
            const int dy = tap / 3;
            const int dx = tap % 3 - 1;
            const int slot = out_row + dy;
            const int apx  = px_tile + m + 1 + dx;
            #pragma unroll
            for (int ks = 0; ks < 2; ++ks) {
                const int k0 = ks * 16;
                bf16x8 a = *(const bf16x8*)(lds + lds_off(slot, apx, k0 + hi * 8));
                bf16x8 b = *(const bf16x8*)(wB +
                    (((size_t)tap * 32 + ((icg0 + k0) >> 3) + hi) * 32 + m) * 8);
                acc = __builtin_amdgcn_mfma_f32_32x32x16_bf16(b, a, acc, 0, 0, 0);
            }
        }
        __syncthreads();
    }

    // C/D layout: col(px)=lane&31, row(oc)=(r&3)+8*(r>>2)+4*hi
    float vals[16];
    float mx = -3.0e38f;
    #pragma unroll
    for (int r = 0; r < 16; ++r) {
        int oc = (r & 3) + 8 * (r >> 2) + 4 * hi;
        float v = -3.0e38f;
        if (oc < NOC) {
            float sc = gamma[oc] * rsqrtf(rvar[oc] + EPSBN);
            float b  = beta[oc] - rmean[oc] * sc;
            v = fmaf(acc[r], sc, b);
        }
        vals[r] = v;
        mx = fmaxf(mx, v);
    }
    mx = fmaxf(mx, __shfl_xor(mx, 32));
    float s = 0.0f;
    #pragma unroll
    for (int r = 0; r < 16; ++r) {
        int oc = (r & 3) + 8 * (r >> 2) + 4 * hi;
        float e = (oc < NOC) ? __expf(vals[r] - mx) : 0.0f;
        vals[r] = e;
        s += e;
    }
    s += __shfl_xor(s, 32);
    const float inv = 1.0f / s;

    float* so = sigma + (size_t)n * NOC * PLANE
              + (size_t)(y0 + out_row) * HW + px_tile + m;
    #pragma unroll
    for (int r = 0; r < 16; ++r) {
        int oc = (r & 3) + 8 * (r >> 2) + 4 * hi;
        if (oc < NOC) so[(size_t)oc * PLANE] = vals[r] * inv;
    }
}

// ------------- Kernel B: per-pixel dynamic 3x3 pooling ---------------------
// grid: 2048 blocks (n(8) x chsplit(8) x yq(32)); each thread: 16 channels.
__global__ __launch_bounds__(256) void pasa_pool(
    const float* __restrict__ x, const float* __restrict__ sigma,
    float* __restrict__ out)
{
    int flat = blockIdx.x;                 // [0,2048)
    int nf   = (flat & 7) * 256 + (flat >> 3);   // XCD owns one image
    const int n       = nf >> 8;
    const int chsplit = (nf >> 5) & 7;
    const int yq      = nf & 31;

    const int q = threadIdx.x & 31;
    const int r = (threadIdx.x >> 5) & 3;
    const int s = threadIdx.x >> 7;        // group 0/1

    const int y   = yq * 4 + r;
    const int px0 = q * 4;

    const int ym = (y == 0)      ? 1      : y - 1;
    const int yp = (y == HW - 1) ? HW - 2 : y + 1;
    const int lx = (px0 == 0)        ? 1      : px0 - 1;
    const int rx = (px0 + 4 > HW - 1)? HW - 2 : px0 + 4;

    const float* sg = sigma + ((size_t)n * NOC + s * 9) * PLANE
                            + (size_t)y * HW + px0;
    float sgv[9][4];
    #pragma unroll
    for (int k = 0; k < 9; ++k) {
        float4 t = *(const float4*)(sg + (size_t)k * PLANE);
        sgv[k][0] = t.x; sgv[k][1] = t.y; sgv[k][2] = t.z; sgv[k][3] = t.w;
    }

    const int c0 = s * 128 + chsplit * 16;
    const float* xn = x + (size_t)n * NCH * PLANE;
    float*       on = out + (size_t)n * NCH * PLANE;

    for (int cc = 0; cc < 16; ++cc) {
        const int c = c0 + cc;
        const float* xc = xn + (size_t)c * PLANE;
        const float* rws[3] = { xc + (size_t)ym * HW, xc + (size_t)y * HW,
                                xc + (size_t)yp * HW };
        float ov[4] = {0.f, 0.f, 0.f, 0.f};
        #pragma unroll
        for (int dy = 0; dy < 3; ++dy) {
            const float* rr = rws[dy];
            float  w0 = rr[lx];
            float4 mm = *(const float4*)(rr + px0);
            float  w5 = rr[rx];
            float wvv[6] = { w0, mm.x, mm.y, mm.z, mm.w, w5 };
            #pragma unroll
            for (int j = 0; j < 4; ++j) {
                #pragma unroll
                for (int dx = 0; dx < 3; ++dx)
                    ov[j] = fmaf(wvv[j + dx], sgv[dy * 3 + dx][j], ov[j]);
            }
        }
        float4 o4 = { ov[0], ov[1], ov[2], ov[3] };
        *(float4*)(on + (size_t)c * PLANE + (size_t)y * HW + px0) = o4;
    }
}

extern "C" void kernel_launch(void* const* d_in, const int* in_sizes, int n_in,
                              void* d_out, int out_size, void* d_ws, size_t ws_size,
                              hipStream_t stream) {
    const float* x     = (const float*)d_in[0];
    const float* w     = (const float*)d_in[1];
    const float* gamma = (const float*)d_in[2];
    const float* beta  = (const float*)d_in[3];
    const float* rmean = (const float*)d_in[4];
    const float* rvar  = (const float*)d_in[5];
    float* out   = (float*)d_out;
    float* sigma = (float*)d_ws;                 // 8*18*16384*4 = 9.44 MB

    unsigned short* wB = (unsigned short*)((char*)d_out + (size_t)64 * 1024 * 1024);

    pasa_wprep<<<dim3(288), dim3(256), 0, stream>>>(w, wB);
    pasa_conv_mfma<<<dim3(512), dim3(512), 0, stream>>>(
        x, wB, gamma, beta, rmean, rvar, sigma);
    pasa_pool<<<dim3(2048), dim3(256), 0, stream>>>(x, sigma, out);
}